// Round 1
// baseline (507.541 us; speedup 1.0000x reference)
//
#include <hip/hip_runtime.h>

#define N_NODES 50000
#define IN_SIZE 512
#define HID 128
#define OUT 64
#define SCAN_NB 196   // 196*256 = 50176 >= 50000

// ---------- edge-index dtype detection (int32 vs int64 layout) ----------
__global__ void k_detect(const int* __restrict__ p, int* __restrict__ flag) {
    if (threadIdx.x == 0 && blockIdx.x == 0) {
        int odd_zero = 1;
        for (int i = 1; i < 129; i += 2) {
            if (p[i] != 0) { odd_zero = 0; break; }
        }
        *flag = odd_zero;   // 1 => data is int64, 0 => int32
    }
}

__device__ __forceinline__ int load_idx(const void* p, int e, bool w) {
    return w ? (int)((const long long*)p)[e] : ((const int*)p)[e];
}

// ---------- degree histogram ----------
__global__ __launch_bounds__(256) void k_histo(const void* __restrict__ srcp,
                                               const void* __restrict__ dstp,
                                               const int* __restrict__ flag,
                                               int* __restrict__ cnt_out,
                                               int* __restrict__ cnt_in, int E) {
    int e = blockIdx.x * 256 + threadIdx.x;
    if (e >= E) return;
    bool w = (*flag) != 0;
    int s = load_idx(srcp, e, w);
    int d = load_idx(dstp, e, w);
    atomicAdd(&cnt_out[s], 1);
    atomicAdd(&cnt_in[d], 1);
}

// ---------- norms ----------
__global__ __launch_bounds__(256) void k_norm(const int* __restrict__ co, const int* __restrict__ ci,
                                              float* __restrict__ on, float* __restrict__ inn) {
    int i = blockIdx.x * 256 + threadIdx.x;
    if (i >= N_NODES) return;
    int a = co[i]; if (a < 1) a = 1;
    int b = ci[i]; if (b < 1) b = 1;
    on[i]  = 1.0f / sqrtf((float)a);
    inn[i] = 1.0f / sqrtf((float)b);
}

// ---------- exclusive scan of cnt_in -> row_ptr (3-kernel) ----------
__global__ __launch_bounds__(256) void k_scan_a(const int* __restrict__ cnt, int* __restrict__ excl,
                                                int* __restrict__ bsum) {
    __shared__ int s[256];
    int i = blockIdx.x * 256 + threadIdx.x;
    int v = (i < N_NODES) ? cnt[i] : 0;
    s[threadIdx.x] = v;
    __syncthreads();
    for (int off = 1; off < 256; off <<= 1) {
        int t = (threadIdx.x >= off) ? s[threadIdx.x - off] : 0;
        __syncthreads();
        s[threadIdx.x] += t;
        __syncthreads();
    }
    if (i < N_NODES) excl[i] = s[threadIdx.x] - v;
    if (threadIdx.x == 255) bsum[blockIdx.x] = s[255];
}

__global__ __launch_bounds__(256) void k_scan_b(const int* __restrict__ bsum, int* __restrict__ boffs,
                                                int* __restrict__ rp_last) {
    __shared__ int s[256];
    int i = threadIdx.x;
    int v = (i < SCAN_NB) ? bsum[i] : 0;
    s[i] = v;
    __syncthreads();
    for (int off = 1; off < 256; off <<= 1) {
        int t = (i >= off) ? s[i - off] : 0;
        __syncthreads();
        s[i] += t;
        __syncthreads();
    }
    boffs[i] = s[i] - v;
    if (i == 255) rp_last[0] = s[255];
}

__global__ __launch_bounds__(256) void k_scan_c(int* __restrict__ rp, const int* __restrict__ boffs,
                                                int* __restrict__ cursor) {
    int i = blockIdx.x * 256 + threadIdx.x;
    if (i >= N_NODES) return;
    int r = rp[i] + boffs[blockIdx.x];
    rp[i] = r;
    cursor[i] = r;
}

// ---------- bucket edges by dst (CSR build) ----------
__global__ __launch_bounds__(256) void k_bucket(const void* __restrict__ srcp, const void* __restrict__ dstp,
                                                const int* __restrict__ flag, int* __restrict__ cursor,
                                                int* __restrict__ esrc, int E) {
    int e = blockIdx.x * 256 + threadIdx.x;
    if (e >= E) return;
    bool w = (*flag) != 0;
    int s = load_idx(srcp, e, w);
    int d = load_idx(dstp, e, w);
    int pos = atomicAdd(&cursor[d], 1);
    esrc[pos] = s;
}

// ---------- GEMM1: X1[n,:] = out_norm[n] * (feat[n,:] @ W1)   [50000x512 @ 512x128] ----------
__global__ __launch_bounds__(256) void k_gemm1(const float* __restrict__ A, const float* __restrict__ B,
                                               const float* __restrict__ onorm, float* __restrict__ X) {
    __shared__ float As[32][36];     // 32 rows x 32 k, pad->36 (keeps float4 alignment)
    __shared__ float Bs[32][128];    // 32 k x 128 cols
    const int tid  = threadIdx.x;
    const int row0 = blockIdx.x * 32;
    const int c  = (tid & 15) * 8;   // 8 output cols
    const int r0 = (tid >> 4) * 2;   // 2 output rows
    const int am = tid >> 3, ak = (tid & 7) * 4;
    const int bc = (tid & 31) * 4, bk = tid >> 5;
    int arow = row0 + am; if (arow >= N_NODES) arow = N_NODES - 1;

    float acc[2][8];
#pragma unroll
    for (int i = 0; i < 2; ++i)
#pragma unroll
        for (int j = 0; j < 8; ++j) acc[i][j] = 0.f;

    for (int k0 = 0; k0 < IN_SIZE; k0 += 32) {
        float4 av = *(const float4*)&A[(size_t)arow * IN_SIZE + k0 + ak];
        float4 b0 = *(const float4*)&B[(size_t)(k0 + bk     ) * HID + bc];
        float4 b1 = *(const float4*)&B[(size_t)(k0 + bk +  8) * HID + bc];
        float4 b2 = *(const float4*)&B[(size_t)(k0 + bk + 16) * HID + bc];
        float4 b3 = *(const float4*)&B[(size_t)(k0 + bk + 24) * HID + bc];
        __syncthreads();
        *(float4*)&As[am][ak]       = av;
        *(float4*)&Bs[bk][bc]       = b0;
        *(float4*)&Bs[bk +  8][bc]  = b1;
        *(float4*)&Bs[bk + 16][bc]  = b2;
        *(float4*)&Bs[bk + 24][bc]  = b3;
        __syncthreads();
#pragma unroll 8
        for (int kk = 0; kk < 32; ++kk) {
            float a0 = As[r0][kk];
            float a1 = As[r0 + 1][kk];
            float4 u = *(const float4*)&Bs[kk][c];
            float4 v = *(const float4*)&Bs[kk][c + 4];
            acc[0][0] += a0 * u.x; acc[0][1] += a0 * u.y; acc[0][2] += a0 * u.z; acc[0][3] += a0 * u.w;
            acc[0][4] += a0 * v.x; acc[0][5] += a0 * v.y; acc[0][6] += a0 * v.z; acc[0][7] += a0 * v.w;
            acc[1][0] += a1 * u.x; acc[1][1] += a1 * u.y; acc[1][2] += a1 * u.z; acc[1][3] += a1 * u.w;
            acc[1][4] += a1 * v.x; acc[1][5] += a1 * v.y; acc[1][6] += a1 * v.z; acc[1][7] += a1 * v.w;
        }
    }
#pragma unroll
    for (int i = 0; i < 2; ++i) {
        int row = row0 + r0 + i;
        if (row < N_NODES) {
            float on = onorm[row];
            float4 o0 = make_float4(acc[i][0] * on, acc[i][1] * on, acc[i][2] * on, acc[i][3] * on);
            float4 o1 = make_float4(acc[i][4] * on, acc[i][5] * on, acc[i][6] * on, acc[i][7] * on);
            *(float4*)&X[(size_t)row * HID + c]     = o0;
            *(float4*)&X[(size_t)row * HID + c + 4] = o1;
        }
    }
}

// ---------- agg1: H[n,:] = relu(sum_{e->n} X1[src] * in_norm[n] + b1) * out_norm[n] ----------
__global__ __launch_bounds__(128) void k_agg1(const float* __restrict__ X, const int* __restrict__ rp,
                                              const int* __restrict__ esrc, const float* __restrict__ innorm,
                                              const float* __restrict__ onorm, const float* __restrict__ b1,
                                              float* __restrict__ H) {
    const int n = blockIdx.x;
    const int j = threadIdx.x;
    const int e0 = rp[n], e1 = rp[n + 1];
    float acc = 0.f;
    int e = e0;
    for (; e + 3 < e1; e += 4) {
        int s0 = esrc[e], s1 = esrc[e + 1], s2 = esrc[e + 2], s3 = esrc[e + 3];
        float v0 = X[(size_t)s0 * HID + j];
        float v1 = X[(size_t)s1 * HID + j];
        float v2 = X[(size_t)s2 * HID + j];
        float v3 = X[(size_t)s3 * HID + j];
        acc += (v0 + v1) + (v2 + v3);
    }
    for (; e < e1; ++e) acc += X[(size_t)esrc[e] * HID + j];
    float h = acc * innorm[n] + b1[j];
    h = fmaxf(h, 0.f) * onorm[n];
    H[(size_t)n * HID + j] = h;
}

// ---------- GEMM2: X2 = H @ W2   [50000x128 @ 128x64], W2 fully in LDS ----------
__global__ __launch_bounds__(256) void k_gemm2(const float* __restrict__ Hm, const float* __restrict__ W2,
                                               float* __restrict__ X2) {
    __shared__ float Ws[HID * OUT];   // 32 KB
    __shared__ float As[32][132];     // 32 rows x 128 k, pad->132
    const int tid  = threadIdx.x;
    const int row0 = blockIdx.x * 32;
    for (int i = tid * 4; i < HID * OUT; i += 1024)
        *(float4*)&Ws[i] = *(const float4*)&W2[i];
    const int am = tid >> 3, ak = (tid & 7) * 4;
    int arow = row0 + am; if (arow >= N_NODES) arow = N_NODES - 1;
#pragma unroll
    for (int kc = 0; kc < HID; kc += 32)
        *(float4*)&As[am][kc + ak] = *(const float4*)&Hm[(size_t)arow * HID + kc + ak];
    __syncthreads();
    const int r  = tid >> 3;
    const int c8 = (tid & 7) * 8;
    float acc[8];
#pragma unroll
    for (int j = 0; j < 8; ++j) acc[j] = 0.f;
#pragma unroll 4
    for (int k = 0; k < HID; ++k) {
        float a = As[r][k];
        float4 u = *(const float4*)&Ws[k * OUT + c8];
        float4 v = *(const float4*)&Ws[k * OUT + c8 + 4];
        acc[0] += a * u.x; acc[1] += a * u.y; acc[2] += a * u.z; acc[3] += a * u.w;
        acc[4] += a * v.x; acc[5] += a * v.y; acc[6] += a * v.z; acc[7] += a * v.w;
    }
    int row = row0 + r;
    if (row < N_NODES) {
        *(float4*)&X2[(size_t)row * OUT + c8]     = make_float4(acc[0], acc[1], acc[2], acc[3]);
        *(float4*)&X2[(size_t)row * OUT + c8 + 4] = make_float4(acc[4], acc[5], acc[6], acc[7]);
    }
}

// ---------- agg2: out[n,:] = sum_{e->n} X2[src] * in_norm[n] + b2 ----------
__global__ __launch_bounds__(256) void k_agg2(const float* __restrict__ X2, const int* __restrict__ rp,
                                              const int* __restrict__ esrc, const float* __restrict__ innorm,
                                              const float* __restrict__ b2, float* __restrict__ out) {
    const int n = blockIdx.x * 4 + (threadIdx.x >> 6);
    const int j = threadIdx.x & 63;
    if (n >= N_NODES) return;
    const int e0 = rp[n], e1 = rp[n + 1];
    float acc = 0.f;
    int e = e0;
    for (; e + 3 < e1; e += 4) {
        int s0 = esrc[e], s1 = esrc[e + 1], s2 = esrc[e + 2], s3 = esrc[e + 3];
        float v0 = X2[(size_t)s0 * OUT + j];
        float v1 = X2[(size_t)s1 * OUT + j];
        float v2 = X2[(size_t)s2 * OUT + j];
        float v3 = X2[(size_t)s3 * OUT + j];
        acc += (v0 + v1) + (v2 + v3);
    }
    for (; e < e1; ++e) acc += X2[(size_t)esrc[e] * OUT + j];
    out[(size_t)n * OUT + j] = acc * innorm[n] + b2[j];
}

extern "C" void kernel_launch(void* const* d_in, const int* in_sizes, int n_in,
                              void* d_out, int out_size, void* d_ws, size_t ws_size,
                              hipStream_t stream) {
    const float* feat = (const float*)d_in[0];
    const float* W1   = (const float*)d_in[1];
    const float* b1   = (const float*)d_in[2];
    const float* W2   = (const float*)d_in[3];
    const float* b2   = (const float*)d_in[4];
    const void*  srcp = d_in[5];
    const void*  dstp = d_in[6];
    const int    E    = in_sizes[5];
    float* out = (float*)d_out;

    char* w = (char*)d_ws;
    size_t off = 0;
    auto alloc = [&](size_t bytes) -> void* {
        off = (off + 255) & ~(size_t)255;
        void* p = w + off;
        off += bytes;
        return p;
    };
    int*   cnt_out = (int*)alloc((size_t)N_NODES * 4);
    int*   cnt_in  = (int*)alloc((size_t)N_NODES * 4);
    int*   rp      = (int*)alloc((size_t)(N_NODES + 1) * 4);
    int*   cursor  = (int*)alloc((size_t)N_NODES * 4);
    int*   bsum    = (int*)alloc(256 * 4);
    int*   boffs   = (int*)alloc(256 * 4);
    int*   flag    = (int*)alloc(4);
    int*   esrc    = (int*)alloc((size_t)E * 4);
    float* onorm   = (float*)alloc((size_t)N_NODES * 4);
    float* innorm  = (float*)alloc((size_t)N_NODES * 4);
    float* X1      = (float*)alloc((size_t)N_NODES * HID * 4);
    float* Hbuf    = (float*)alloc((size_t)N_NODES * HID * 4);
    float* X2      = (float*)alloc((size_t)N_NODES * OUT * 4);
    (void)ws_size; (void)n_in; (void)out_size;

    hipMemsetAsync(cnt_out, 0, (size_t)N_NODES * 4, stream);
    hipMemsetAsync(cnt_in,  0, (size_t)N_NODES * 4, stream);

    k_detect<<<1, 64, 0, stream>>>((const int*)dstp, flag);
    int eb = (E + 255) / 256;
    k_histo<<<eb, 256, 0, stream>>>(srcp, dstp, flag, cnt_out, cnt_in, E);
    k_norm<<<(N_NODES + 255) / 256, 256, 0, stream>>>(cnt_out, cnt_in, onorm, innorm);
    k_scan_a<<<SCAN_NB, 256, 0, stream>>>(cnt_in, rp, bsum);
    k_scan_b<<<1, 256, 0, stream>>>(bsum, boffs, rp + N_NODES);
    k_scan_c<<<SCAN_NB, 256, 0, stream>>>(rp, boffs, cursor);
    k_bucket<<<eb, 256, 0, stream>>>(srcp, dstp, flag, cursor, esrc, E);
    k_gemm1<<<(N_NODES + 31) / 32, 256, 0, stream>>>(feat, W1, onorm, X1);
    k_agg1<<<N_NODES, 128, 0, stream>>>(X1, rp, esrc, innorm, onorm, b1, Hbuf);
    k_gemm2<<<(N_NODES + 31) / 32, 256, 0, stream>>>(Hbuf, W2, X2);
    k_agg2<<<(N_NODES + 3) / 4, 256, 0, stream>>>(X2, rp, esrc, innorm, b2, out);
}

// Round 2
// 429.611 us; speedup vs baseline: 1.1814x; 1.1814x over previous
//
#include <hip/hip_runtime.h>

#define N_NODES 50000
#define IN_SIZE 512
#define HID 128
#define OUT 64
#define SCAN_NB 196   // 196*256 = 50176 >= 50000

typedef _Float16 f16x8 __attribute__((ext_vector_type(8)));
typedef float    f32x4 __attribute__((ext_vector_type(4)));

// ---------- edge-index dtype detection (int32 vs int64 layout) ----------
__global__ void k_detect(const int* __restrict__ p, int* __restrict__ flag) {
    if (threadIdx.x == 0 && blockIdx.x == 0) {
        int odd_zero = 1;
        for (int i = 1; i < 129; i += 2) {
            if (p[i] != 0) { odd_zero = 0; break; }
        }
        *flag = odd_zero;   // 1 => data is int64, 0 => int32
    }
}

__device__ __forceinline__ int load_idx(const void* p, int e, bool w) {
    return w ? (int)((const long long*)p)[e] : ((const int*)p)[e];
}

// ---------- degree histogram ----------
__global__ __launch_bounds__(256) void k_histo(const void* __restrict__ srcp,
                                               const void* __restrict__ dstp,
                                               const int* __restrict__ flag,
                                               int* __restrict__ cnt_out,
                                               int* __restrict__ cnt_in, int E) {
    int e = blockIdx.x * 256 + threadIdx.x;
    if (e >= E) return;
    bool w = (*flag) != 0;
    int s = load_idx(srcp, e, w);
    int d = load_idx(dstp, e, w);
    atomicAdd(&cnt_out[s], 1);
    atomicAdd(&cnt_in[d], 1);
}

// ---------- norms ----------
__global__ __launch_bounds__(256) void k_norm(const int* __restrict__ co, const int* __restrict__ ci,
                                              float* __restrict__ on, float* __restrict__ inn) {
    int i = blockIdx.x * 256 + threadIdx.x;
    if (i >= N_NODES) return;
    int a = co[i]; if (a < 1) a = 1;
    int b = ci[i]; if (b < 1) b = 1;
    on[i]  = 1.0f / sqrtf((float)a);
    inn[i] = 1.0f / sqrtf((float)b);
}

// ---------- exclusive scan of cnt_in -> row_ptr (3-kernel) ----------
__global__ __launch_bounds__(256) void k_scan_a(const int* __restrict__ cnt, int* __restrict__ excl,
                                                int* __restrict__ bsum) {
    __shared__ int s[256];
    int i = blockIdx.x * 256 + threadIdx.x;
    int v = (i < N_NODES) ? cnt[i] : 0;
    s[threadIdx.x] = v;
    __syncthreads();
    for (int off = 1; off < 256; off <<= 1) {
        int t = (threadIdx.x >= off) ? s[threadIdx.x - off] : 0;
        __syncthreads();
        s[threadIdx.x] += t;
        __syncthreads();
    }
    if (i < N_NODES) excl[i] = s[threadIdx.x] - v;
    if (threadIdx.x == 255) bsum[blockIdx.x] = s[255];
}

__global__ __launch_bounds__(256) void k_scan_b(const int* __restrict__ bsum, int* __restrict__ boffs,
                                                int* __restrict__ rp_last) {
    __shared__ int s[256];
    int i = threadIdx.x;
    int v = (i < SCAN_NB) ? bsum[i] : 0;
    s[i] = v;
    __syncthreads();
    for (int off = 1; off < 256; off <<= 1) {
        int t = (i >= off) ? s[i - off] : 0;
        __syncthreads();
        s[i] += t;
        __syncthreads();
    }
    boffs[i] = s[i] - v;
    if (i == 255) rp_last[0] = s[255];
}

__global__ __launch_bounds__(256) void k_scan_c(int* __restrict__ rp, const int* __restrict__ boffs,
                                                int* __restrict__ cursor) {
    int i = blockIdx.x * 256 + threadIdx.x;
    if (i >= N_NODES) return;
    int r = rp[i] + boffs[blockIdx.x];
    rp[i] = r;
    cursor[i] = r;
}

// ---------- bucket edges by dst (CSR build) ----------
__global__ __launch_bounds__(256) void k_bucket(const void* __restrict__ srcp, const void* __restrict__ dstp,
                                                const int* __restrict__ flag, int* __restrict__ cursor,
                                                int* __restrict__ esrc, int E) {
    int e = blockIdx.x * 256 + threadIdx.x;
    if (e >= E) return;
    bool w = (*flag) != 0;
    int s = load_idx(srcp, e, w);
    int d = load_idx(dstp, e, w);
    int pos = atomicAdd(&cursor[d], 1);
    esrc[pos] = s;
}

// ---------- W1 -> W1T fp16 [HID][IN_SIZE] (transposed, once per call) ----------
__global__ __launch_bounds__(256) void k_w1t(const float* __restrict__ W1, _Float16* __restrict__ W1T) {
    int i = blockIdx.x * 256 + threadIdx.x;
    if (i >= IN_SIZE * HID) return;
    int k = i >> 7;        // row of W1 (k index)
    int n = i & (HID - 1); // col of W1
    W1T[(size_t)n * IN_SIZE + k] = (_Float16)W1[i];
}

// ---------- GEMM1 (MFMA fp16): X1[n,:] = out_norm[n] * (feat[n,:] @ W1) ----------
// Block: 256 thr (4 waves), tile 64 rows x 128 cols, BK=32.
// Wave w computes rows [w*16, w*16+16) x all 128 cols (8 n-tiles of 16).
#define LDA 40  // 32 + 8 halfs pad (16B) -> <=2-way bank aliasing on b128 reads
__global__ __launch_bounds__(256) void k_gemm1_mfma(const float* __restrict__ A,
                                                    const _Float16* __restrict__ BT,
                                                    const float* __restrict__ onorm,
                                                    float* __restrict__ X) {
    __shared__ _Float16 As[64 * LDA];
    __shared__ _Float16 Bs[128 * LDA];
    const int tid  = threadIdx.x;
    const int wave = tid >> 6, lane = tid & 63;
    const int lm = lane & 15, lq = lane >> 4;
    const int row0 = blockIdx.x * 64;

    // A staging: thread t -> row ar = t>>2, k-chunk aq = t&3 (8 floats)
    const int ar = tid >> 2, aq = tid & 3;
    int arow = row0 + ar; if (arow >= N_NODES) arow = N_NODES - 1;
    const float* aptr = A + (size_t)arow * IN_SIZE + aq * 8;
    _Float16* asd = &As[ar * LDA + aq * 8];
    // B staging: thread t -> n = t>>1, half h = t&1 (16 halfs)
    const int bn = tid >> 1, bh = tid & 1;
    const _Float16* bptr = BT + (size_t)bn * IN_SIZE + bh * 16;
    _Float16* bsd = &Bs[bn * LDA + bh * 16];

    f32x4 acc[8];
#pragma unroll
    for (int nt = 0; nt < 8; ++nt) acc[nt] = (f32x4){0.f, 0.f, 0.f, 0.f};

    for (int k0 = 0; k0 < IN_SIZE; k0 += 32) {
        float4 a0 = *(const float4*)(aptr + k0);
        float4 a1 = *(const float4*)(aptr + k0 + 4);
        f16x8  b0 = *(const f16x8*)(bptr + k0);
        f16x8  b1 = *(const f16x8*)(bptr + k0 + 8);
        f16x8 ap = {(_Float16)a0.x, (_Float16)a0.y, (_Float16)a0.z, (_Float16)a0.w,
                    (_Float16)a1.x, (_Float16)a1.y, (_Float16)a1.z, (_Float16)a1.w};
        __syncthreads();
        *(f16x8*)asd       = ap;
        *(f16x8*)bsd       = b0;
        *(f16x8*)(bsd + 8) = b1;
        __syncthreads();
        f16x8 af = *(const f16x8*)&As[(wave * 16 + lm) * LDA + lq * 8];
#pragma unroll
        for (int nt = 0; nt < 8; ++nt) {
            f16x8 bf = *(const f16x8*)&Bs[(nt * 16 + lm) * LDA + lq * 8];
            acc[nt] = __builtin_amdgcn_mfma_f32_16x16x32_f16(af, bf, acc[nt], 0, 0, 0);
        }
    }
    // C/D layout: col = lane&15, row = (lane>>4)*4 + i
#pragma unroll
    for (int i = 0; i < 4; ++i) {
        int row = row0 + wave * 16 + lq * 4 + i;
        if (row < N_NODES) {
            float on = onorm[row];
            float* o = X + (size_t)row * HID + lm;
#pragma unroll
            for (int nt = 0; nt < 8; ++nt)
                o[nt * 16] = acc[nt][i] * on;
        }
    }
}

// ---------- agg1: H[n,:] = relu(sum_{e->n} X1[src] * in_norm[n] + b1) * out_norm[n] ----------
__global__ __launch_bounds__(128) void k_agg1(const float* __restrict__ X, const int* __restrict__ rp,
                                              const int* __restrict__ esrc, const float* __restrict__ innorm,
                                              const float* __restrict__ onorm, const float* __restrict__ b1,
                                              float* __restrict__ H) {
    const int n = blockIdx.x;
    const int j = threadIdx.x;
    const int e0 = rp[n], e1 = rp[n + 1];
    float acc = 0.f;
    int e = e0;
    for (; e + 3 < e1; e += 4) {
        int s0 = esrc[e], s1 = esrc[e + 1], s2 = esrc[e + 2], s3 = esrc[e + 3];
        float v0 = X[(size_t)s0 * HID + j];
        float v1 = X[(size_t)s1 * HID + j];
        float v2 = X[(size_t)s2 * HID + j];
        float v3 = X[(size_t)s3 * HID + j];
        acc += (v0 + v1) + (v2 + v3);
    }
    for (; e < e1; ++e) acc += X[(size_t)esrc[e] * HID + j];
    float h = acc * innorm[n] + b1[j];
    h = fmaxf(h, 0.f) * onorm[n];
    H[(size_t)n * HID + j] = h;
}

// ---------- GEMM2: X2 = H @ W2   [50000x128 @ 128x64], W2 fully in LDS ----------
__global__ __launch_bounds__(256) void k_gemm2(const float* __restrict__ Hm, const float* __restrict__ W2,
                                               float* __restrict__ X2) {
    __shared__ float Ws[HID * OUT];   // 32 KB
    __shared__ float As[32][132];     // 32 rows x 128 k, pad->132
    const int tid  = threadIdx.x;
    const int row0 = blockIdx.x * 32;
    for (int i = tid * 4; i < HID * OUT; i += 1024)
        *(float4*)&Ws[i] = *(const float4*)&W2[i];
    const int am = tid >> 3, ak = (tid & 7) * 4;
    int arow = row0 + am; if (arow >= N_NODES) arow = N_NODES - 1;
#pragma unroll
    for (int kc = 0; kc < HID; kc += 32)
        *(float4*)&As[am][kc + ak] = *(const float4*)&Hm[(size_t)arow * HID + kc + ak];
    __syncthreads();
    const int r  = tid >> 3;
    const int c8 = (tid & 7) * 8;
    float acc[8];
#pragma unroll
    for (int j = 0; j < 8; ++j) acc[j] = 0.f;
#pragma unroll 4
    for (int k = 0; k < HID; ++k) {
        float a = As[r][k];
        float4 u = *(const float4*)&Ws[k * OUT + c8];
        float4 v = *(const float4*)&Ws[k * OUT + c8 + 4];
        acc[0] += a * u.x; acc[1] += a * u.y; acc[2] += a * u.z; acc[3] += a * u.w;
        acc[4] += a * v.x; acc[5] += a * v.y; acc[6] += a * v.z; acc[7] += a * v.w;
    }
    int row = row0 + r;
    if (row < N_NODES) {
        *(float4*)&X2[(size_t)row * OUT + c8]     = make_float4(acc[0], acc[1], acc[2], acc[3]);
        *(float4*)&X2[(size_t)row * OUT + c8 + 4] = make_float4(acc[4], acc[5], acc[6], acc[7]);
    }
}

// ---------- agg2: out[n,:] = sum_{e->n} X2[src] * in_norm[n] + b2 ----------
__global__ __launch_bounds__(256) void k_agg2(const float* __restrict__ X2, const int* __restrict__ rp,
                                              const int* __restrict__ esrc, const float* __restrict__ innorm,
                                              const float* __restrict__ b2, float* __restrict__ out) {
    const int n = blockIdx.x * 4 + (threadIdx.x >> 6);
    const int j = threadIdx.x & 63;
    if (n >= N_NODES) return;
    const int e0 = rp[n], e1 = rp[n + 1];
    float acc = 0.f;
    int e = e0;
    for (; e + 3 < e1; e += 4) {
        int s0 = esrc[e], s1 = esrc[e + 1], s2 = esrc[e + 2], s3 = esrc[e + 3];
        float v0 = X2[(size_t)s0 * OUT + j];
        float v1 = X2[(size_t)s1 * OUT + j];
        float v2 = X2[(size_t)s2 * OUT + j];
        float v3 = X2[(size_t)s3 * OUT + j];
        acc += (v0 + v1) + (v2 + v3);
    }
    for (; e < e1; ++e) acc += X2[(size_t)esrc[e] * OUT + j];
    out[(size_t)n * OUT + j] = acc * innorm[n] + b2[j];
}

extern "C" void kernel_launch(void* const* d_in, const int* in_sizes, int n_in,
                              void* d_out, int out_size, void* d_ws, size_t ws_size,
                              hipStream_t stream) {
    const float* feat = (const float*)d_in[0];
    const float* W1   = (const float*)d_in[1];
    const float* b1   = (const float*)d_in[2];
    const float* W2   = (const float*)d_in[3];
    const float* b2   = (const float*)d_in[4];
    const void*  srcp = d_in[5];
    const void*  dstp = d_in[6];
    const int    E    = in_sizes[5];
    float* out = (float*)d_out;

    char* w = (char*)d_ws;
    size_t off = 0;
    auto alloc = [&](size_t bytes) -> void* {
        off = (off + 255) & ~(size_t)255;
        void* p = w + off;
        off += bytes;
        return p;
    };
    int*   cnt_out = (int*)alloc((size_t)N_NODES * 4);
    int*   cnt_in  = (int*)alloc((size_t)N_NODES * 4);
    int*   rp      = (int*)alloc((size_t)(N_NODES + 1) * 4);
    int*   cursor  = (int*)alloc((size_t)N_NODES * 4);
    int*   bsum    = (int*)alloc(256 * 4);
    int*   boffs   = (int*)alloc(256 * 4);
    int*   flag    = (int*)alloc(4);
    int*   esrc    = (int*)alloc((size_t)E * 4);
    float* onorm   = (float*)alloc((size_t)N_NODES * 4);
    float* innorm  = (float*)alloc((size_t)N_NODES * 4);
    _Float16* W1T  = (_Float16*)alloc((size_t)IN_SIZE * HID * 2);
    float* X1      = (float*)alloc((size_t)N_NODES * HID * 4);
    float* Hbuf    = (float*)alloc((size_t)N_NODES * HID * 4);
    float* X2      = (float*)alloc((size_t)N_NODES * OUT * 4);
    (void)ws_size; (void)n_in; (void)out_size;

    hipMemsetAsync(cnt_out, 0, (size_t)N_NODES * 4, stream);
    hipMemsetAsync(cnt_in,  0, (size_t)N_NODES * 4, stream);

    k_detect<<<1, 64, 0, stream>>>((const int*)dstp, flag);
    int eb = (E + 255) / 256;
    k_histo<<<eb, 256, 0, stream>>>(srcp, dstp, flag, cnt_out, cnt_in, E);
    k_norm<<<(N_NODES + 255) / 256, 256, 0, stream>>>(cnt_out, cnt_in, onorm, innorm);
    k_scan_a<<<SCAN_NB, 256, 0, stream>>>(cnt_in, rp, bsum);
    k_scan_b<<<1, 256, 0, stream>>>(bsum, boffs, rp + N_NODES);
    k_scan_c<<<SCAN_NB, 256, 0, stream>>>(rp, boffs, cursor);
    k_bucket<<<eb, 256, 0, stream>>>(srcp, dstp, flag, cursor, esrc, E);
    k_w1t<<<(IN_SIZE * HID + 255) / 256, 256, 0, stream>>>(W1, W1T);
    k_gemm1_mfma<<<(N_NODES + 63) / 64, 256, 0, stream>>>(feat, W1T, onorm, X1);
    k_agg1<<<N_NODES, 128, 0, stream>>>(X1, rp, esrc, innorm, onorm, b1, Hbuf);
    k_gemm2<<<(N_NODES + 31) / 32, 256, 0, stream>>>(Hbuf, W2, X2);
    k_agg2<<<(N_NODES + 3) / 4, 256, 0, stream>>>(X2, rp, esrc, innorm, b2, out);
}

// Round 3
// 387.657 us; speedup vs baseline: 1.3093x; 1.1082x over previous
//
#include <hip/hip_runtime.h>

#define N_NODES 50000
#define IN_SIZE 512
#define HID 128
#define OUT 64
#define NB 256                 // coarse scatter blocks
#define SHIFT 7                // bucket = dst >> 7  (128 nodes per bucket)
#define NBUCK 391              // ceil(50000/128)

typedef _Float16 f16x8 __attribute__((ext_vector_type(8)));
typedef float    f32x4 __attribute__((ext_vector_type(4)));

// ---------- edge-index dtype detection (int32 vs int64 layout) ----------
__global__ void k_detect(const int* __restrict__ p, int* __restrict__ flag) {
    if (threadIdx.x == 0 && blockIdx.x == 0) {
        int odd_zero = 1;
        for (int i = 1; i < 129; i += 2) {
            if (p[i] != 0) { odd_zero = 0; break; }
        }
        *flag = odd_zero;   // 1 => data is int64, 0 => int32
    }
}

__device__ __forceinline__ int load_idx(const void* p, int e, bool w) {
    return w ? (int)((const long long*)p)[e] : ((const int*)p)[e];
}

// ---------- src-side degree histogram (global atomics, 800k) ----------
__global__ __launch_bounds__(256) void k_histo_src(const void* __restrict__ srcp,
                                                   const int* __restrict__ flag,
                                                   int* __restrict__ cnt_out, int E) {
    int e = blockIdx.x * 256 + threadIdx.x;
    if (e >= E) return;
    bool w = (*flag) != 0;
    atomicAdd(&cnt_out[load_idx(srcp, e, w)], 1);
}

__global__ __launch_bounds__(256) void k_norm_out(const int* __restrict__ co, float* __restrict__ on) {
    int i = blockIdx.x * 256 + threadIdx.x;
    if (i >= N_NODES) return;
    int a = co[i]; if (a < 1) a = 1;
    on[i] = 1.0f / sqrtf((float)a);
}

// ---------- pass 1: per-block coarse histogram of dst (LDS only) ----------
__global__ __launch_bounds__(256) void k_chist(const void* __restrict__ dstp,
                                               const int* __restrict__ flag,
                                               int* __restrict__ hist, int E, int EPB) {
    __shared__ int bins[NBUCK];
    const int t = threadIdx.x, b = blockIdx.x;
    for (int i = t; i < NBUCK; i += 256) bins[i] = 0;
    __syncthreads();
    bool w = (*flag) != 0;
    int eend = min(E, (b + 1) * EPB);
    for (int e = b * EPB + t; e < eend; e += 256)
        atomicAdd(&bins[load_idx(dstp, e, w) >> SHIFT], 1);
    __syncthreads();
    for (int i = t; i < NBUCK; i += 256) hist[i * NB + b] = bins[i];
}

// ---------- pass 2: scan hist (bucket-major). scanA blocks == buckets ----------
__global__ __launch_bounds__(256) void k_scanA(int* __restrict__ hist, int* __restrict__ bsum) {
    __shared__ int s[256];
    const int t = threadIdx.x, g = blockIdx.x;
    int v = hist[g * NB + t];
    s[t] = v;
    __syncthreads();
    for (int off = 1; off < 256; off <<= 1) {
        int u = (t >= off) ? s[t - off] : 0;
        __syncthreads();
        s[t] += u;
        __syncthreads();
    }
    hist[g * NB + t] = s[t] - v;          // block-local exclusive
    if (t == 255) bsum[g] = s[255];       // bucket total
}

__global__ __launch_bounds__(512) void k_scanB(const int* __restrict__ bsum, int* __restrict__ bb) {
    __shared__ int s[512];
    const int t = threadIdx.x;
    int v = (t < NBUCK) ? bsum[t] : 0;
    s[t] = v;
    __syncthreads();
    for (int off = 1; off < 512; off <<= 1) {
        int u = (t >= off) ? s[t - off] : 0;
        __syncthreads();
        s[t] += u;
        __syncthreads();
    }
    if (t <= NBUCK) bb[t] = s[t] - v;     // bb[NBUCK] = total = E
}

__global__ __launch_bounds__(256) void k_scanC(int* __restrict__ hist, const int* __restrict__ bb) {
    const int t = threadIdx.x, g = blockIdx.x;
    hist[g * NB + t] += bb[g];
}

// ---------- pass 3: coarse scatter (src, dst&127) via LDS cursors ----------
__global__ __launch_bounds__(256) void k_cscatter(const void* __restrict__ srcp,
                                                  const void* __restrict__ dstp,
                                                  const int* __restrict__ flag,
                                                  const int* __restrict__ hist,
                                                  int* __restrict__ tmp_src,
                                                  unsigned char* __restrict__ tmp_dl,
                                                  int E, int EPB) {
    __shared__ int cur[NBUCK];
    const int t = threadIdx.x, b = blockIdx.x;
    for (int i = t; i < NBUCK; i += 256) cur[i] = hist[i * NB + b];
    __syncthreads();
    bool w = (*flag) != 0;
    int eend = min(E, (b + 1) * EPB);
    for (int e = b * EPB + t; e < eend; e += 256) {
        int s = load_idx(srcp, e, w);
        int d = load_idx(dstp, e, w);
        int pos = atomicAdd(&cur[d >> SHIFT], 1);
        tmp_src[pos] = s;
        tmp_dl[pos]  = (unsigned char)(d & 127);
    }
}

// ---------- pass 4: fine count + scan + scatter into CSR; writes rp, innorm ----------
__global__ __launch_bounds__(256) void k_fine(const int* __restrict__ tmp_src,
                                              const unsigned char* __restrict__ tmp_dl,
                                              const int* __restrict__ bb,
                                              int* __restrict__ rp,
                                              int* __restrict__ esrc,
                                              float* __restrict__ innorm) {
    __shared__ int fcnt[128];
    __shared__ int sc[128];
    __shared__ int fcur[128];
    const int t = threadIdx.x, u = blockIdx.x;
    const int e0 = bb[u], e1 = bb[u + 1];
    if (t < 128) fcnt[t] = 0;
    __syncthreads();
    for (int e = e0 + t; e < e1; e += 256)
        atomicAdd(&fcnt[tmp_dl[e]], 1);
    __syncthreads();
    if (t < 128) sc[t] = fcnt[t];
    __syncthreads();
    for (int off = 1; off < 128; off <<= 1) {
        int v = (t < 128 && t >= off) ? sc[t - off] : 0;
        __syncthreads();
        if (t < 128) sc[t] += v;
        __syncthreads();
    }
    if (t < 128) {
        int base = e0 + sc[t] - fcnt[t];
        fcur[t] = base;
        int node = u * 128 + t;
        if (node < N_NODES) {
            rp[node] = base;
            int c = fcnt[t]; if (c < 1) c = 1;
            innorm[node] = 1.0f / sqrtf((float)c);
        }
    }
    if (u == NBUCK - 1 && t == 0) rp[N_NODES] = e1;
    __syncthreads();
    for (int e = e0 + t; e < e1; e += 256) {
        int pos = atomicAdd(&fcur[tmp_dl[e]], 1);
        esrc[pos] = tmp_src[e];
    }
}

// ---------- W1 -> W1T fp16 [HID][IN_SIZE] (transposed, once per call) ----------
__global__ __launch_bounds__(256) void k_w1t(const float* __restrict__ W1, _Float16* __restrict__ W1T) {
    int i = blockIdx.x * 256 + threadIdx.x;
    if (i >= IN_SIZE * HID) return;
    int k = i >> 7;        // row of W1 (k index)
    int n = i & (HID - 1); // col of W1
    W1T[(size_t)n * IN_SIZE + k] = (_Float16)W1[i];
}

// ---------- GEMM1 (MFMA fp16): X1[n,:] = out_norm[n] * (feat[n,:] @ W1) ----------
#define LDA 40  // 32 + 8 halfs pad (16B) -> <=2-way bank aliasing on b128 reads
__global__ __launch_bounds__(256) void k_gemm1_mfma(const float* __restrict__ A,
                                                    const _Float16* __restrict__ BT,
                                                    const float* __restrict__ onorm,
                                                    float* __restrict__ X) {
    __shared__ _Float16 As[64 * LDA];
    __shared__ _Float16 Bs[128 * LDA];
    const int tid  = threadIdx.x;
    const int wave = tid >> 6, lane = tid & 63;
    const int lm = lane & 15, lq = lane >> 4;
    const int row0 = blockIdx.x * 64;

    const int ar = tid >> 2, aq = tid & 3;
    int arow = row0 + ar; if (arow >= N_NODES) arow = N_NODES - 1;
    const float* aptr = A + (size_t)arow * IN_SIZE + aq * 8;
    _Float16* asd = &As[ar * LDA + aq * 8];
    const int bn = tid >> 1, bh = tid & 1;
    const _Float16* bptr = BT + (size_t)bn * IN_SIZE + bh * 16;
    _Float16* bsd = &Bs[bn * LDA + bh * 16];

    f32x4 acc[8];
#pragma unroll
    for (int nt = 0; nt < 8; ++nt) acc[nt] = (f32x4){0.f, 0.f, 0.f, 0.f};

    for (int k0 = 0; k0 < IN_SIZE; k0 += 32) {
        float4 a0 = *(const float4*)(aptr + k0);
        float4 a1 = *(const float4*)(aptr + k0 + 4);
        f16x8  b0 = *(const f16x8*)(bptr + k0);
        f16x8  b1 = *(const f16x8*)(bptr + k0 + 8);
        f16x8 ap = {(_Float16)a0.x, (_Float16)a0.y, (_Float16)a0.z, (_Float16)a0.w,
                    (_Float16)a1.x, (_Float16)a1.y, (_Float16)a1.z, (_Float16)a1.w};
        __syncthreads();
        *(f16x8*)asd       = ap;
        *(f16x8*)bsd       = b0;
        *(f16x8*)(bsd + 8) = b1;
        __syncthreads();
        f16x8 af = *(const f16x8*)&As[(wave * 16 + lm) * LDA + lq * 8];
#pragma unroll
        for (int nt = 0; nt < 8; ++nt) {
            f16x8 bf = *(const f16x8*)&Bs[(nt * 16 + lm) * LDA + lq * 8];
            acc[nt] = __builtin_amdgcn_mfma_f32_16x16x32_f16(af, bf, acc[nt], 0, 0, 0);
        }
    }
#pragma unroll
    for (int i = 0; i < 4; ++i) {
        int row = row0 + wave * 16 + lq * 4 + i;
        if (row < N_NODES) {
            float on = onorm[row];
            float* o = X + (size_t)row * HID + lm;
#pragma unroll
            for (int nt = 0; nt < 8; ++nt)
                o[nt * 16] = acc[nt][i] * on;
        }
    }
}

// ---------- agg1: H[n,:] = relu(sum_{e->n} X1[src] * in_norm[n] + b1) * out_norm[n] ----------
__global__ __launch_bounds__(128) void k_agg1(const float* __restrict__ X, const int* __restrict__ rp,
                                              const int* __restrict__ esrc, const float* __restrict__ innorm,
                                              const float* __restrict__ onorm, const float* __restrict__ b1,
                                              float* __restrict__ H) {
    const int n = blockIdx.x;
    const int j = threadIdx.x;
    const int e0 = rp[n], e1 = rp[n + 1];
    float acc = 0.f;
    int e = e0;
    for (; e + 3 < e1; e += 4) {
        int s0 = esrc[e], s1 = esrc[e + 1], s2 = esrc[e + 2], s3 = esrc[e + 3];
        float v0 = X[(size_t)s0 * HID + j];
        float v1 = X[(size_t)s1 * HID + j];
        float v2 = X[(size_t)s2 * HID + j];
        float v3 = X[(size_t)s3 * HID + j];
        acc += (v0 + v1) + (v2 + v3);
    }
    for (; e < e1; ++e) acc += X[(size_t)esrc[e] * HID + j];
    float h = acc * innorm[n] + b1[j];
    h = fmaxf(h, 0.f) * onorm[n];
    H[(size_t)n * HID + j] = h;
}

// ---------- GEMM2: X2 = H @ W2   [50000x128 @ 128x64], W2 fully in LDS ----------
__global__ __launch_bounds__(256) void k_gemm2(const float* __restrict__ Hm, const float* __restrict__ W2,
                                               float* __restrict__ X2) {
    __shared__ float Ws[HID * OUT];   // 32 KB
    __shared__ float As[32][132];     // 32 rows x 128 k, pad->132
    const int tid  = threadIdx.x;
    const int row0 = blockIdx.x * 32;
    for (int i = tid * 4; i < HID * OUT; i += 1024)
        *(float4*)&Ws[i] = *(const float4*)&W2[i];
    const int am = tid >> 3, ak = (tid & 7) * 4;
    int arow = row0 + am; if (arow >= N_NODES) arow = N_NODES - 1;
#pragma unroll
    for (int kc = 0; kc < HID; kc += 32)
        *(float4*)&As[am][kc + ak] = *(const float4*)&Hm[(size_t)arow * HID + kc + ak];
    __syncthreads();
    const int r  = tid >> 3;
    const int c8 = (tid & 7) * 8;
    float acc[8];
#pragma unroll
    for (int j = 0; j < 8; ++j) acc[j] = 0.f;
#pragma unroll 4
    for (int k = 0; k < HID; ++k) {
        float a = As[r][k];
        float4 u = *(const float4*)&Ws[k * OUT + c8];
        float4 v = *(const float4*)&Ws[k * OUT + c8 + 4];
        acc[0] += a * u.x; acc[1] += a * u.y; acc[2] += a * u.z; acc[3] += a * u.w;
        acc[4] += a * v.x; acc[5] += a * v.y; acc[6] += a * v.z; acc[7] += a * v.w;
    }
    int row = row0 + r;
    if (row < N_NODES) {
        *(float4*)&X2[(size_t)row * OUT + c8]     = make_float4(acc[0], acc[1], acc[2], acc[3]);
        *(float4*)&X2[(size_t)row * OUT + c8 + 4] = make_float4(acc[4], acc[5], acc[6], acc[7]);
    }
}

// ---------- agg2: out[n,:] = sum_{e->n} X2[src] * in_norm[n] + b2 ----------
__global__ __launch_bounds__(256) void k_agg2(const float* __restrict__ X2, const int* __restrict__ rp,
                                              const int* __restrict__ esrc, const float* __restrict__ innorm,
                                              const float* __restrict__ b2, float* __restrict__ out) {
    const int n = blockIdx.x * 4 + (threadIdx.x >> 6);
    const int j = threadIdx.x & 63;
    if (n >= N_NODES) return;
    const int e0 = rp[n], e1 = rp[n + 1];
    float acc = 0.f;
    int e = e0;
    for (; e + 3 < e1; e += 4) {
        int s0 = esrc[e], s1 = esrc[e + 1], s2 = esrc[e + 2], s3 = esrc[e + 3];
        float v0 = X2[(size_t)s0 * OUT + j];
        float v1 = X2[(size_t)s1 * OUT + j];
        float v2 = X2[(size_t)s2 * OUT + j];
        float v3 = X2[(size_t)s3 * OUT + j];
        acc += (v0 + v1) + (v2 + v3);
    }
    for (; e < e1; ++e) acc += X2[(size_t)esrc[e] * OUT + j];
    out[(size_t)n * OUT + j] = acc * innorm[n] + b2[j];
}

extern "C" void kernel_launch(void* const* d_in, const int* in_sizes, int n_in,
                              void* d_out, int out_size, void* d_ws, size_t ws_size,
                              hipStream_t stream) {
    const float* feat = (const float*)d_in[0];
    const float* W1   = (const float*)d_in[1];
    const float* b1   = (const float*)d_in[2];
    const float* W2   = (const float*)d_in[3];
    const float* b2   = (const float*)d_in[4];
    const void*  srcp = (const void*)d_in[5];
    const void*  dstp = (const void*)d_in[6];
    const int    E    = in_sizes[5];
    float* out = (float*)d_out;

    char* w = (char*)d_ws;
    size_t off = 0;
    auto alloc = [&](size_t bytes) -> void* {
        off = (off + 255) & ~(size_t)255;
        void* p = w + off;
        off += bytes;
        return p;
    };
    int*   cnt_out = (int*)alloc((size_t)N_NODES * 4);
    int*   hist    = (int*)alloc((size_t)NBUCK * NB * 4);
    int*   bsum    = (int*)alloc((size_t)NBUCK * 4);
    int*   bb      = (int*)alloc((size_t)(NBUCK + 1) * 4);
    int*   rp      = (int*)alloc((size_t)(N_NODES + 1) * 4);
    int*   flag    = (int*)alloc(4);
    int*   tmp_src = (int*)alloc((size_t)E * 4);
    unsigned char* tmp_dl = (unsigned char*)alloc((size_t)E);
    int*   esrc    = (int*)alloc((size_t)E * 4);
    float* onorm   = (float*)alloc((size_t)N_NODES * 4);
    float* innorm  = (float*)alloc((size_t)N_NODES * 4);
    _Float16* W1T  = (_Float16*)alloc((size_t)IN_SIZE * HID * 2);
    float* X1      = (float*)alloc((size_t)N_NODES * HID * 4);
    float* Hbuf    = (float*)alloc((size_t)N_NODES * HID * 4);
    float* X2      = (float*)alloc((size_t)N_NODES * OUT * 4);
    (void)ws_size; (void)n_in; (void)out_size;

    const int EPB = (E + NB - 1) / NB;
    const int eb  = (E + 255) / 256;

    hipMemsetAsync(cnt_out, 0, (size_t)N_NODES * 4, stream);
    k_detect<<<1, 64, 0, stream>>>((const int*)dstp, flag);

    // CSR build (dst side, LDS-atomic counting sort)
    k_chist<<<NB, 256, 0, stream>>>(dstp, flag, hist, E, EPB);
    k_scanA<<<NBUCK, 256, 0, stream>>>(hist, bsum);
    k_scanB<<<1, 512, 0, stream>>>(bsum, bb);
    k_scanC<<<NBUCK, 256, 0, stream>>>(hist, bb);
    k_cscatter<<<NB, 256, 0, stream>>>(srcp, dstp, flag, hist, tmp_src, tmp_dl, E, EPB);
    k_fine<<<NBUCK, 256, 0, stream>>>(tmp_src, tmp_dl, bb, rp, esrc, innorm);

    // out-degree (src side)
    k_histo_src<<<eb, 256, 0, stream>>>(srcp, flag, cnt_out, E);
    k_norm_out<<<(N_NODES + 255) / 256, 256, 0, stream>>>(cnt_out, onorm);

    // dense + aggregation pipeline
    k_w1t<<<(IN_SIZE * HID + 255) / 256, 256, 0, stream>>>(W1, W1T);
    k_gemm1_mfma<<<(N_NODES + 63) / 64, 256, 0, stream>>>(feat, W1T, onorm, X1);
    k_agg1<<<N_NODES, 128, 0, stream>>>(X1, rp, esrc, innorm, onorm, b1, Hbuf);
    k_gemm2<<<(N_NODES + 31) / 32, 256, 0, stream>>>(Hbuf, W2, X2);
    k_agg2<<<(N_NODES + 3) / 4, 256, 0, stream>>>(X2, rp, esrc, innorm, b2, out);
}

// Round 4
// 323.356 us; speedup vs baseline: 1.5696x; 1.1989x over previous
//
#include <hip/hip_runtime.h>

#define N_NODES 50000
#define IN_SIZE 512
#define HID 128
#define OUT 64
#define NB 256                 // coarse scatter blocks
#define SHIFT 7                // bucket = dst >> 7  (128 nodes per bucket)
#define NBUCK 391              // ceil(50000/128)

typedef _Float16 f16x8 __attribute__((ext_vector_type(8)));
typedef _Float16 f16x2 __attribute__((ext_vector_type(2)));
typedef float    f32x4 __attribute__((ext_vector_type(4)));

// ---------- edge-index dtype detection (int32 vs int64 layout) ----------
__global__ void k_detect(const int* __restrict__ p, int* __restrict__ flag) {
    if (threadIdx.x == 0 && blockIdx.x == 0) {
        int odd_zero = 1;
        for (int i = 1; i < 129; i += 2) {
            if (p[i] != 0) { odd_zero = 0; break; }
        }
        *flag = odd_zero;   // 1 => data is int64, 0 => int32
    }
}

__device__ __forceinline__ int load_idx(const void* p, int e, bool w) {
    return w ? (int)((const long long*)p)[e] : ((const int*)p)[e];
}

// ---------- pass 1: per-block coarse histogram of dst (LDS only) ----------
__global__ __launch_bounds__(256) void k_chist(const void* __restrict__ dstp,
                                               const int* __restrict__ flag,
                                               int* __restrict__ hist, int E, int EPB) {
    __shared__ int bins[NBUCK];
    const int t = threadIdx.x, b = blockIdx.x;
    for (int i = t; i < NBUCK; i += 256) bins[i] = 0;
    __syncthreads();
    bool w = (*flag) != 0;
    int eend = min(E, (b + 1) * EPB);
    for (int e = b * EPB + t; e < eend; e += 256)
        atomicAdd(&bins[load_idx(dstp, e, w) >> SHIFT], 1);
    __syncthreads();
    for (int i = t; i < NBUCK; i += 256) hist[i * NB + b] = bins[i];
}

// ---------- pass 2: scan hist (bucket-major) ----------
__global__ __launch_bounds__(256) void k_scanA(int* __restrict__ hist, int* __restrict__ bsum) {
    __shared__ int s[256];
    const int t = threadIdx.x, g = blockIdx.x;
    int v = hist[g * NB + t];
    s[t] = v;
    __syncthreads();
    for (int off = 1; off < 256; off <<= 1) {
        int u = (t >= off) ? s[t - off] : 0;
        __syncthreads();
        s[t] += u;
        __syncthreads();
    }
    hist[g * NB + t] = s[t] - v;          // block-local exclusive
    if (t == 255) bsum[g] = s[255];       // bucket total
}

__global__ __launch_bounds__(512) void k_scanB(const int* __restrict__ bsum, int* __restrict__ bb) {
    __shared__ int s[512];
    const int t = threadIdx.x;
    int v = (t < NBUCK) ? bsum[t] : 0;
    s[t] = v;
    __syncthreads();
    for (int off = 1; off < 512; off <<= 1) {
        int u = (t >= off) ? s[t - off] : 0;
        __syncthreads();
        s[t] += u;
        __syncthreads();
    }
    if (t <= NBUCK) bb[t] = s[t] - v;     // bb[NBUCK] = total = E
}

__global__ __launch_bounds__(256) void k_scanC(int* __restrict__ hist, const int* __restrict__ bb) {
    const int t = threadIdx.x, g = blockIdx.x;
    hist[g * NB + t] += bb[g];
}

// ---------- pass 3: coarse scatter + fused src-degree histogram ----------
__global__ __launch_bounds__(256) void k_cscatter(const void* __restrict__ srcp,
                                                  const void* __restrict__ dstp,
                                                  const int* __restrict__ flag,
                                                  const int* __restrict__ hist,
                                                  int* __restrict__ tmp_src,
                                                  unsigned char* __restrict__ tmp_dl,
                                                  int* __restrict__ cnt_out,
                                                  int E, int EPB) {
    __shared__ int cur[NBUCK];
    const int t = threadIdx.x, b = blockIdx.x;
    for (int i = t; i < NBUCK; i += 256) cur[i] = hist[i * NB + b];
    __syncthreads();
    bool w = (*flag) != 0;
    int eend = min(E, (b + 1) * EPB);
    for (int e = b * EPB + t; e < eend; e += 256) {
        int s = load_idx(srcp, e, w);
        int d = load_idx(dstp, e, w);
        atomicAdd(&cnt_out[s], 1);           // fused out-degree histogram
        int pos = atomicAdd(&cur[d >> SHIFT], 1);
        tmp_src[pos] = s;
        tmp_dl[pos]  = (unsigned char)(d & 127);
    }
}

// ---------- pass 4: fine count + scan + scatter; writes rp, innorm, onorm ----------
__global__ __launch_bounds__(256) void k_fine(const int* __restrict__ tmp_src,
                                              const unsigned char* __restrict__ tmp_dl,
                                              const int* __restrict__ bb,
                                              const int* __restrict__ cnt_out,
                                              int* __restrict__ rp,
                                              int* __restrict__ esrc,
                                              float* __restrict__ innorm,
                                              float* __restrict__ onorm) {
    __shared__ int fcnt[128];
    __shared__ int sc[128];
    __shared__ int fcur[128];
    const int t = threadIdx.x, u = blockIdx.x;
    const int e0 = bb[u], e1 = bb[u + 1];
    if (t < 128) fcnt[t] = 0;
    __syncthreads();
    for (int e = e0 + t; e < e1; e += 256)
        atomicAdd(&fcnt[tmp_dl[e]], 1);
    __syncthreads();
    if (t < 128) sc[t] = fcnt[t];
    __syncthreads();
    for (int off = 1; off < 128; off <<= 1) {
        int v = (t < 128 && t >= off) ? sc[t - off] : 0;
        __syncthreads();
        if (t < 128) sc[t] += v;
        __syncthreads();
    }
    if (t < 128) {
        int base = e0 + sc[t] - fcnt[t];
        fcur[t] = base;
        int node = u * 128 + t;
        if (node < N_NODES) {
            rp[node] = base;
            int c = fcnt[t]; if (c < 1) c = 1;
            innorm[node] = 1.0f / sqrtf((float)c);
            int a = cnt_out[node]; if (a < 1) a = 1;
            onorm[node] = 1.0f / sqrtf((float)a);
        }
    }
    if (u == NBUCK - 1 && t == 0) rp[N_NODES] = e1;
    __syncthreads();
    for (int e = e0 + t; e < e1; e += 256) {
        int pos = atomicAdd(&fcur[tmp_dl[e]], 1);
        esrc[pos] = tmp_src[e];
    }
}

// ---------- weight transposes -> fp16 (merged, once per call) ----------
__global__ __launch_bounds__(256) void k_wt(const float* __restrict__ W1, _Float16* __restrict__ W1T,
                                            const float* __restrict__ W2, _Float16* __restrict__ W2T) {
    int i = blockIdx.x * 256 + threadIdx.x;
    if (i < IN_SIZE * HID) {
        int k = i >> 7, n = i & (HID - 1);
        W1T[(size_t)n * IN_SIZE + k] = (_Float16)W1[i];
    } else {
        int j = i - IN_SIZE * HID;
        if (j < HID * OUT) {
            int k = j >> 6, n = j & (OUT - 1);
            W2T[(size_t)n * HID + k] = (_Float16)W2[j];
        }
    }
}

// ---------- GEMM1 (MFMA fp16): X1[n,:] = fp16( out_norm[n] * (feat[n,:] @ W1) ) ----------
#define LDA 40  // 32 + 8 halfs pad (16B)
__global__ __launch_bounds__(256) void k_gemm1_mfma(const float* __restrict__ A,
                                                    const _Float16* __restrict__ BT,
                                                    const float* __restrict__ onorm,
                                                    _Float16* __restrict__ X) {
    __shared__ _Float16 As[64 * LDA];
    __shared__ _Float16 Bs[128 * LDA];
    const int tid  = threadIdx.x;
    const int wave = tid >> 6, lane = tid & 63;
    const int lm = lane & 15, lq = lane >> 4;
    const int row0 = blockIdx.x * 64;

    const int ar = tid >> 2, aq = tid & 3;
    int arow = row0 + ar; if (arow >= N_NODES) arow = N_NODES - 1;
    const float* aptr = A + (size_t)arow * IN_SIZE + aq * 8;
    _Float16* asd = &As[ar * LDA + aq * 8];
    const int bn = tid >> 1, bh = tid & 1;
    const _Float16* bptr = BT + (size_t)bn * IN_SIZE + bh * 16;
    _Float16* bsd = &Bs[bn * LDA + bh * 16];

    f32x4 acc[8];
#pragma unroll
    for (int nt = 0; nt < 8; ++nt) acc[nt] = (f32x4){0.f, 0.f, 0.f, 0.f};

    for (int k0 = 0; k0 < IN_SIZE; k0 += 32) {
        float4 a0 = *(const float4*)(aptr + k0);
        float4 a1 = *(const float4*)(aptr + k0 + 4);
        f16x8  b0 = *(const f16x8*)(bptr + k0);
        f16x8  b1 = *(const f16x8*)(bptr + k0 + 8);
        f16x8 ap = {(_Float16)a0.x, (_Float16)a0.y, (_Float16)a0.z, (_Float16)a0.w,
                    (_Float16)a1.x, (_Float16)a1.y, (_Float16)a1.z, (_Float16)a1.w};
        __syncthreads();
        *(f16x8*)asd       = ap;
        *(f16x8*)bsd       = b0;
        *(f16x8*)(bsd + 8) = b1;
        __syncthreads();
        f16x8 af = *(const f16x8*)&As[(wave * 16 + lm) * LDA + lq * 8];
#pragma unroll
        for (int nt = 0; nt < 8; ++nt) {
            f16x8 bf = *(const f16x8*)&Bs[(nt * 16 + lm) * LDA + lq * 8];
            acc[nt] = __builtin_amdgcn_mfma_f32_16x16x32_f16(af, bf, acc[nt], 0, 0, 0);
        }
    }
#pragma unroll
    for (int i = 0; i < 4; ++i) {
        int row = row0 + wave * 16 + lq * 4 + i;
        if (row < N_NODES) {
            float on = onorm[row];
            _Float16* o = X + (size_t)row * HID + lm;
#pragma unroll
            for (int nt = 0; nt < 8; ++nt)
                o[nt * 16] = (_Float16)(acc[nt][i] * on);
        }
    }
}

// ---------- agg1: H = fp16( relu(gather-sum(X1)*in_norm + b1) * out_norm ) ----------
// one wave per node; lane handles 2 contiguous cols (4B loads)
__global__ __launch_bounds__(256) void k_agg1(const _Float16* __restrict__ X, const int* __restrict__ rp,
                                              const int* __restrict__ esrc, const float* __restrict__ innorm,
                                              const float* __restrict__ onorm, const float* __restrict__ b1,
                                              _Float16* __restrict__ H) {
    const int n = blockIdx.x * 4 + (threadIdx.x >> 6);
    const int c = (threadIdx.x & 63) << 1;
    if (n >= N_NODES) return;
    const int e0 = rp[n], e1 = rp[n + 1];
    float a0 = 0.f, a1 = 0.f;
    int e = e0;
    for (; e + 3 < e1; e += 4) {
        int s0 = esrc[e], s1 = esrc[e + 1], s2 = esrc[e + 2], s3 = esrc[e + 3];
        f16x2 v0 = *(const f16x2*)&X[(size_t)s0 * HID + c];
        f16x2 v1 = *(const f16x2*)&X[(size_t)s1 * HID + c];
        f16x2 v2 = *(const f16x2*)&X[(size_t)s2 * HID + c];
        f16x2 v3 = *(const f16x2*)&X[(size_t)s3 * HID + c];
        a0 += ((float)v0.x + (float)v1.x) + ((float)v2.x + (float)v3.x);
        a1 += ((float)v0.y + (float)v1.y) + ((float)v2.y + (float)v3.y);
    }
    for (; e < e1; ++e) {
        f16x2 v = *(const f16x2*)&X[(size_t)esrc[e] * HID + c];
        a0 += (float)v.x; a1 += (float)v.y;
    }
    float inn = innorm[n], on = onorm[n];
    float2 b = *(const float2*)&b1[c];
    float h0 = fmaxf(a0 * inn + b.x, 0.f) * on;
    float h1 = fmaxf(a1 * inn + b.y, 0.f) * on;
    *(f16x2*)&H[(size_t)n * HID + c] = (f16x2){(_Float16)h0, (_Float16)h1};
}

// ---------- GEMM2 (MFMA fp16): X2 = fp16( H @ W2 )   [50000x128 @ 128x64] ----------
#define LDK 136  // 128 + 8 halfs pad
__global__ __launch_bounds__(256) void k_gemm2_mfma(const _Float16* __restrict__ Hm,
                                                    const _Float16* __restrict__ W2T,
                                                    _Float16* __restrict__ X2) {
    __shared__ _Float16 Hs[64 * LDK];
    __shared__ _Float16 Ws[64 * LDK];
    const int tid  = threadIdx.x;
    const int wave = tid >> 6, lane = tid & 63;
    const int lm = lane & 15, lq = lane >> 4;
    const int row0 = blockIdx.x * 64;

    // stage: thread t -> row r=t>>2, chunk c=(t&3)*32 halfs (4 x f16x8)
    const int r = tid >> 2, cch = (tid & 3) * 32;
    int hrow = row0 + r; if (hrow >= N_NODES) hrow = N_NODES - 1;
    const _Float16* hp = Hm + (size_t)hrow * HID + cch;
    const _Float16* wp = W2T + (size_t)r * HID + cch;
    _Float16* hd = &Hs[r * LDK + cch];
    _Float16* wd = &Ws[r * LDK + cch];
#pragma unroll
    for (int i = 0; i < 4; ++i) {
        *(f16x8*)(hd + i * 8) = *(const f16x8*)(hp + i * 8);
        *(f16x8*)(wd + i * 8) = *(const f16x8*)(wp + i * 8);
    }
    __syncthreads();

    f32x4 acc[4];
#pragma unroll
    for (int nt = 0; nt < 4; ++nt) acc[nt] = (f32x4){0.f, 0.f, 0.f, 0.f};
#pragma unroll
    for (int k0 = 0; k0 < HID; k0 += 32) {
        f16x8 af = *(const f16x8*)&Hs[(wave * 16 + lm) * LDK + k0 + lq * 8];
#pragma unroll
        for (int nt = 0; nt < 4; ++nt) {
            f16x8 bf = *(const f16x8*)&Ws[(nt * 16 + lm) * LDK + k0 + lq * 8];
            acc[nt] = __builtin_amdgcn_mfma_f32_16x16x32_f16(af, bf, acc[nt], 0, 0, 0);
        }
    }
#pragma unroll
    for (int i = 0; i < 4; ++i) {
        int row = row0 + wave * 16 + lq * 4 + i;
        if (row < N_NODES) {
            _Float16* o = X2 + (size_t)row * OUT + lm;
#pragma unroll
            for (int nt = 0; nt < 4; ++nt)
                o[nt * 16] = (_Float16)acc[nt][i];
        }
    }
}

// ---------- agg2: out = gather-sum(X2)*in_norm + b2  (fp32 out) ----------
// half-wave (32 lanes) per node; lane handles 2 cols
__global__ __launch_bounds__(256) void k_agg2(const _Float16* __restrict__ X2, const int* __restrict__ rp,
                                              const int* __restrict__ esrc, const float* __restrict__ innorm,
                                              const float* __restrict__ b2, float* __restrict__ out) {
    const int n = blockIdx.x * 8 + (threadIdx.x >> 5);
    const int c = (threadIdx.x & 31) << 1;
    if (n >= N_NODES) return;
    const int e0 = rp[n], e1 = rp[n + 1];
    float a0 = 0.f, a1 = 0.f;
    int e = e0;
    for (; e + 3 < e1; e += 4) {
        int s0 = esrc[e], s1 = esrc[e + 1], s2 = esrc[e + 2], s3 = esrc[e + 3];
        f16x2 v0 = *(const f16x2*)&X2[(size_t)s0 * OUT + c];
        f16x2 v1 = *(const f16x2*)&X2[(size_t)s1 * OUT + c];
        f16x2 v2 = *(const f16x2*)&X2[(size_t)s2 * OUT + c];
        f16x2 v3 = *(const f16x2*)&X2[(size_t)s3 * OUT + c];
        a0 += ((float)v0.x + (float)v1.x) + ((float)v2.x + (float)v3.x);
        a1 += ((float)v0.y + (float)v1.y) + ((float)v2.y + (float)v3.y);
    }
    for (; e < e1; ++e) {
        f16x2 v = *(const f16x2*)&X2[(size_t)esrc[e] * OUT + c];
        a0 += (float)v.x; a1 += (float)v.y;
    }
    float inn = innorm[n];
    float2 b = *(const float2*)&b2[c];
    *(float2*)&out[(size_t)n * OUT + c] = make_float2(a0 * inn + b.x, a1 * inn + b.y);
}

extern "C" void kernel_launch(void* const* d_in, const int* in_sizes, int n_in,
                              void* d_out, int out_size, void* d_ws, size_t ws_size,
                              hipStream_t stream) {
    const float* feat = (const float*)d_in[0];
    const float* W1   = (const float*)d_in[1];
    const float* b1   = (const float*)d_in[2];
    const float* W2   = (const float*)d_in[3];
    const float* b2   = (const float*)d_in[4];
    const void*  srcp = (const void*)d_in[5];
    const void*  dstp = (const void*)d_in[6];
    const int    E    = in_sizes[5];
    float* out = (float*)d_out;

    char* w = (char*)d_ws;
    size_t off = 0;
    auto alloc = [&](size_t bytes) -> void* {
        off = (off + 255) & ~(size_t)255;
        void* p = w + off;
        off += bytes;
        return p;
    };
    int*   cnt_out = (int*)alloc((size_t)N_NODES * 4);
    int*   hist    = (int*)alloc((size_t)NBUCK * NB * 4);
    int*   bsum    = (int*)alloc((size_t)NBUCK * 4);
    int*   bb      = (int*)alloc((size_t)(NBUCK + 1) * 4);
    int*   rp      = (int*)alloc((size_t)(N_NODES + 1) * 4);
    int*   flag    = (int*)alloc(4);
    int*   tmp_src = (int*)alloc((size_t)E * 4);
    unsigned char* tmp_dl = (unsigned char*)alloc((size_t)E);
    int*   esrc    = (int*)alloc((size_t)E * 4);
    float* onorm   = (float*)alloc((size_t)N_NODES * 4);
    float* innorm  = (float*)alloc((size_t)N_NODES * 4);
    _Float16* W1T  = (_Float16*)alloc((size_t)IN_SIZE * HID * 2);
    _Float16* W2T  = (_Float16*)alloc((size_t)HID * OUT * 2);
    _Float16* X1   = (_Float16*)alloc((size_t)N_NODES * HID * 2);
    _Float16* Hbuf = (_Float16*)alloc((size_t)N_NODES * HID * 2);
    _Float16* X2   = (_Float16*)alloc((size_t)N_NODES * OUT * 2);
    (void)ws_size; (void)n_in; (void)out_size;

    const int EPB = (E + NB - 1) / NB;

    hipMemsetAsync(cnt_out, 0, (size_t)N_NODES * 4, stream);
    k_detect<<<1, 64, 0, stream>>>((const int*)dstp, flag);

    // CSR build (dst side, LDS-atomic counting sort) + fused src histogram
    k_chist<<<NB, 256, 0, stream>>>(dstp, flag, hist, E, EPB);
    k_scanA<<<NBUCK, 256, 0, stream>>>(hist, bsum);
    k_scanB<<<1, 512, 0, stream>>>(bsum, bb);
    k_scanC<<<NBUCK, 256, 0, stream>>>(hist, bb);
    k_cscatter<<<NB, 256, 0, stream>>>(srcp, dstp, flag, hist, tmp_src, tmp_dl, cnt_out, E, EPB);
    k_fine<<<NBUCK, 256, 0, stream>>>(tmp_src, tmp_dl, bb, cnt_out, rp, esrc, innorm, onorm);

    // weights -> fp16 transposed
    k_wt<<<(IN_SIZE * HID + HID * OUT + 255) / 256, 256, 0, stream>>>(W1, W1T, W2, W2T);

    // dense + aggregation pipeline
    k_gemm1_mfma<<<(N_NODES + 63) / 64, 256, 0, stream>>>(feat, W1T, onorm, X1);
    k_agg1<<<(N_NODES + 3) / 4, 256, 0, stream>>>(X1, rp, esrc, innorm, onorm, b1, Hbuf);
    k_gemm2_mfma<<<(N_NODES + 63) / 64, 256, 0, stream>>>(Hbuf, W2T, X2);
    k_agg2<<<(N_NODES + 7) / 8, 256, 0, stream>>>(X2, rp, esrc, innorm, b2, out);
}

// Round 5
// 316.628 us; speedup vs baseline: 1.6030x; 1.0212x over previous
//
#include <hip/hip_runtime.h>

#define N_NODES 50000
#define IN_SIZE 512
#define HID 128
#define OUT 64
#define NB 256                 // coarse scatter blocks
#define SHIFT 7                // bucket = dst >> 7  (128 nodes per bucket)
#define NBUCK 391              // ceil(50000/128)
#define SB 64                  // src-histogram blocks (100KB LDS each)
#define NBINS32 25000          // 50000 uint16 bins packed in uint32

typedef _Float16 f16x8 __attribute__((ext_vector_type(8)));
typedef _Float16 f16x2 __attribute__((ext_vector_type(2)));
typedef float    f32x4 __attribute__((ext_vector_type(4)));

// ---------- inline int64-vs-int32 layout detection (per block, no extra dispatch) ----------
// random indices make 64 consecutive zero odd-words impossible for int32 layout
__device__ __forceinline__ bool detect_w(const int* p, int t, int* sh) {
    if (t < 64) {
        unsigned long long m = __ballot(p[2 * t + 1] == 0);
        if (t == 0) *sh = (m == ~0ull) ? 1 : 0;
    }
    __syncthreads();
    return *sh != 0;
}

__device__ __forceinline__ int load_idx(const void* p, int e, bool w) {
    return w ? (int)((const long long*)p)[e] : ((const int*)p)[e];
}

// ---------- pass 1: per-block coarse histogram of dst (LDS only) + appended weight-transpose blocks ----------
__global__ __launch_bounds__(256) void k_chist_wt(const void* __restrict__ dstp,
                                                  int* __restrict__ hist, int E, int EPB,
                                                  const float* __restrict__ W1, _Float16* __restrict__ W1T,
                                                  const float* __restrict__ W2, _Float16* __restrict__ W2T) {
    const int t = threadIdx.x, b = blockIdx.x;
    if (b >= NB) {   // weight transpose tail blocks
        int i = (b - NB) * 256 + t;
        if (i < IN_SIZE * HID) {
            int k = i >> 7, n = i & (HID - 1);
            W1T[(size_t)n * IN_SIZE + k] = (_Float16)W1[i];
        } else {
            int j = i - IN_SIZE * HID;
            if (j < HID * OUT) {
                int k = j >> 6, n = j & (OUT - 1);
                W2T[(size_t)n * HID + k] = (_Float16)W2[j];
            }
        }
        return;
    }
    __shared__ int bins[NBUCK];
    __shared__ int shw;
    for (int i = t; i < NBUCK; i += 256) bins[i] = 0;
    bool w = detect_w((const int*)dstp, t, &shw);   // has its own __syncthreads
    __syncthreads();
    int eend = min(E, (b + 1) * EPB);
    for (int e = b * EPB + t; e < eend; e += 256)
        atomicAdd(&bins[load_idx(dstp, e, w) >> SHIFT], 1);
    __syncthreads();
    for (int i = t; i < NBUCK; i += 256) hist[i * NB + b] = bins[i];
}

// ---------- src out-degree: privatized packed-uint16 LDS histograms (no global atomics) ----------
__global__ __launch_bounds__(256) void k_srchist(const void* __restrict__ srcp,
                                                 unsigned int* __restrict__ partial, int E, int ESB) {
    __shared__ unsigned int bins[NBINS32];   // 100 KB
    __shared__ int shw;
    const int t = threadIdx.x, b = blockIdx.x;
    for (int i = t; i < NBINS32; i += 256) bins[i] = 0;
    bool w = detect_w((const int*)srcp, t, &shw);
    __syncthreads();
    int eend = min(E, (b + 1) * ESB);
    for (int e = b * ESB + t; e < eend; e += 256) {
        int s = load_idx(srcp, e, w);
        atomicAdd(&bins[s >> 1], 1u << ((s & 1) << 4));   // per-block count <= ESB << 65536: no carry
    }
    __syncthreads();
    for (int i = t; i < NBINS32; i += 256) partial[(size_t)b * NBINS32 + i] = bins[i];
}

__global__ __launch_bounds__(256) void k_sred(const unsigned int* __restrict__ partial,
                                              float* __restrict__ onorm) {
    int wd = blockIdx.x * 256 + threadIdx.x;
    if (wd >= NBINS32) return;
    int c0 = 0, c1 = 0;
    for (int b = 0; b < SB; ++b) {
        unsigned int v = partial[(size_t)b * NBINS32 + wd];
        c0 += (int)(v & 0xFFFFu);
        c1 += (int)(v >> 16);
    }
    if (c0 < 1) c0 = 1;
    if (c1 < 1) c1 = 1;
    onorm[2 * wd]     = 1.0f / sqrtf((float)c0);
    onorm[2 * wd + 1] = 1.0f / sqrtf((float)c1);
}

// ---------- pass 2: scan hist (bucket-major) ----------
__global__ __launch_bounds__(256) void k_scanA(int* __restrict__ hist, int* __restrict__ bsum) {
    __shared__ int s[256];
    const int t = threadIdx.x, g = blockIdx.x;
    int v = hist[g * NB + t];
    s[t] = v;
    __syncthreads();
    for (int off = 1; off < 256; off <<= 1) {
        int u = (t >= off) ? s[t - off] : 0;
        __syncthreads();
        s[t] += u;
        __syncthreads();
    }
    hist[g * NB + t] = s[t] - v;          // block-local exclusive (within bucket)
    if (t == 255) bsum[g] = s[255];       // bucket total
}

__global__ __launch_bounds__(512) void k_scanB(const int* __restrict__ bsum, int* __restrict__ bb) {
    __shared__ int s[512];
    const int t = threadIdx.x;
    int v = (t < NBUCK) ? bsum[t] : 0;
    s[t] = v;
    __syncthreads();
    for (int off = 1; off < 512; off <<= 1) {
        int u = (t >= off) ? s[t - off] : 0;
        __syncthreads();
        s[t] += u;
        __syncthreads();
    }
    if (t <= NBUCK) bb[t] = s[t] - v;     // bb[NBUCK] = total = E
}

// ---------- pass 3: coarse scatter (bb folded into cursors; no global atomics) ----------
__global__ __launch_bounds__(256) void k_cscatter(const void* __restrict__ srcp,
                                                  const void* __restrict__ dstp,
                                                  const int* __restrict__ hist,
                                                  const int* __restrict__ bb,
                                                  int* __restrict__ tmp_src,
                                                  unsigned char* __restrict__ tmp_dl,
                                                  int E, int EPB) {
    __shared__ int cur[NBUCK];
    __shared__ int shw;
    const int t = threadIdx.x, b = blockIdx.x;
    for (int i = t; i < NBUCK; i += 256) cur[i] = hist[i * NB + b] + bb[i];
    bool w = detect_w((const int*)dstp, t, &shw);
    __syncthreads();
    int eend = min(E, (b + 1) * EPB);
    for (int e = b * EPB + t; e < eend; e += 256) {
        int s = load_idx(srcp, e, w);
        int d = load_idx(dstp, e, w);
        int pos = atomicAdd(&cur[d >> SHIFT], 1);
        tmp_src[pos] = s;
        tmp_dl[pos]  = (unsigned char)(d & 127);
    }
}

// ---------- pass 4: fine count + scan + scatter; writes rp, innorm ----------
__global__ __launch_bounds__(256) void k_fine(const int* __restrict__ tmp_src,
                                              const unsigned char* __restrict__ tmp_dl,
                                              const int* __restrict__ bb,
                                              int* __restrict__ rp,
                                              int* __restrict__ esrc,
                                              float* __restrict__ innorm) {
    __shared__ int fcnt[128];
    __shared__ int sc[128];
    __shared__ int fcur[128];
    const int t = threadIdx.x, u = blockIdx.x;
    const int e0 = bb[u], e1 = bb[u + 1];
    if (t < 128) fcnt[t] = 0;
    __syncthreads();
    for (int e = e0 + t; e < e1; e += 256)
        atomicAdd(&fcnt[tmp_dl[e]], 1);
    __syncthreads();
    if (t < 128) sc[t] = fcnt[t];
    __syncthreads();
    for (int off = 1; off < 128; off <<= 1) {
        int v = (t < 128 && t >= off) ? sc[t - off] : 0;
        __syncthreads();
        if (t < 128) sc[t] += v;
        __syncthreads();
    }
    if (t < 128) {
        int base = e0 + sc[t] - fcnt[t];
        fcur[t] = base;
        int node = u * 128 + t;
        if (node < N_NODES) {
            rp[node] = base;
            int c = fcnt[t]; if (c < 1) c = 1;
            innorm[node] = 1.0f / sqrtf((float)c);
        }
    }
    if (u == NBUCK - 1 && t == 0) rp[N_NODES] = e1;
    __syncthreads();
    for (int e = e0 + t; e < e1; e += 256) {
        int pos = atomicAdd(&fcur[tmp_dl[e]], 1);
        esrc[pos] = tmp_src[e];
    }
}

// ---------- GEMM1 (MFMA fp16): X1[n,:] = fp16( out_norm[n] * (feat[n,:] @ W1) ) ----------
#define LDA 40  // 32 + 8 halfs pad (16B)
__global__ __launch_bounds__(256) void k_gemm1_mfma(const float* __restrict__ A,
                                                    const _Float16* __restrict__ BT,
                                                    const float* __restrict__ onorm,
                                                    _Float16* __restrict__ X) {
    __shared__ _Float16 As[64 * LDA];
    __shared__ _Float16 Bs[128 * LDA];
    const int tid  = threadIdx.x;
    const int wave = tid >> 6, lane = tid & 63;
    const int lm = lane & 15, lq = lane >> 4;
    const int row0 = blockIdx.x * 64;

    const int ar = tid >> 2, aq = tid & 3;
    int arow = row0 + ar; if (arow >= N_NODES) arow = N_NODES - 1;
    const float* aptr = A + (size_t)arow * IN_SIZE + aq * 8;
    _Float16* asd = &As[ar * LDA + aq * 8];
    const int bn = tid >> 1, bh = tid & 1;
    const _Float16* bptr = BT + (size_t)bn * IN_SIZE + bh * 16;
    _Float16* bsd = &Bs[bn * LDA + bh * 16];

    f32x4 acc[8];
#pragma unroll
    for (int nt = 0; nt < 8; ++nt) acc[nt] = (f32x4){0.f, 0.f, 0.f, 0.f};

    for (int k0 = 0; k0 < IN_SIZE; k0 += 32) {
        float4 a0 = *(const float4*)(aptr + k0);
        float4 a1 = *(const float4*)(aptr + k0 + 4);
        f16x8  b0 = *(const f16x8*)(bptr + k0);
        f16x8  b1 = *(const f16x8*)(bptr + k0 + 8);
        f16x8 ap = {(_Float16)a0.x, (_Float16)a0.y, (_Float16)a0.z, (_Float16)a0.w,
                    (_Float16)a1.x, (_Float16)a1.y, (_Float16)a1.z, (_Float16)a1.w};
        __syncthreads();
        *(f16x8*)asd       = ap;
        *(f16x8*)bsd       = b0;
        *(f16x8*)(bsd + 8) = b1;
        __syncthreads();
        f16x8 af = *(const f16x8*)&As[(wave * 16 + lm) * LDA + lq * 8];
#pragma unroll
        for (int nt = 0; nt < 8; ++nt) {
            f16x8 bf = *(const f16x8*)&Bs[(nt * 16 + lm) * LDA + lq * 8];
            acc[nt] = __builtin_amdgcn_mfma_f32_16x16x32_f16(af, bf, acc[nt], 0, 0, 0);
        }
    }
#pragma unroll
    for (int i = 0; i < 4; ++i) {
        int row = row0 + wave * 16 + lq * 4 + i;
        if (row < N_NODES) {
            float on = onorm[row];
            _Float16* o = X + (size_t)row * HID + lm;
#pragma unroll
            for (int nt = 0; nt < 8; ++nt)
                o[nt * 16] = (_Float16)(acc[nt][i] * on);
        }
    }
}

// ---------- agg1: H = fp16( relu(gather-sum(X1)*in_norm + b1) * out_norm ) ----------
__global__ __launch_bounds__(256) void k_agg1(const _Float16* __restrict__ X, const int* __restrict__ rp,
                                              const int* __restrict__ esrc, const float* __restrict__ innorm,
                                              const float* __restrict__ onorm, const float* __restrict__ b1,
                                              _Float16* __restrict__ H) {
    const int n = blockIdx.x * 4 + (threadIdx.x >> 6);
    const int c = (threadIdx.x & 63) << 1;
    if (n >= N_NODES) return;
    const int e0 = rp[n], e1 = rp[n + 1];
    float a0 = 0.f, a1 = 0.f;
    int e = e0;
    for (; e + 3 < e1; e += 4) {
        int s0 = esrc[e], s1 = esrc[e + 1], s2 = esrc[e + 2], s3 = esrc[e + 3];
        f16x2 v0 = *(const f16x2*)&X[(size_t)s0 * HID + c];
        f16x2 v1 = *(const f16x2*)&X[(size_t)s1 * HID + c];
        f16x2 v2 = *(const f16x2*)&X[(size_t)s2 * HID + c];
        f16x2 v3 = *(const f16x2*)&X[(size_t)s3 * HID + c];
        a0 += ((float)v0.x + (float)v1.x) + ((float)v2.x + (float)v3.x);
        a1 += ((float)v0.y + (float)v1.y) + ((float)v2.y + (float)v3.y);
    }
    for (; e < e1; ++e) {
        f16x2 v = *(const f16x2*)&X[(size_t)esrc[e] * HID + c];
        a0 += (float)v.x; a1 += (float)v.y;
    }
    float inn = innorm[n], on = onorm[n];
    float2 b = *(const float2*)&b1[c];
    float h0 = fmaxf(a0 * inn + b.x, 0.f) * on;
    float h1 = fmaxf(a1 * inn + b.y, 0.f) * on;
    *(f16x2*)&H[(size_t)n * HID + c] = (f16x2){(_Float16)h0, (_Float16)h1};
}

// ---------- GEMM2 (MFMA fp16): X2 = fp16( H @ W2 )   [50000x128 @ 128x64] ----------
#define LDK 136  // 128 + 8 halfs pad
__global__ __launch_bounds__(256) void k_gemm2_mfma(const _Float16* __restrict__ Hm,
                                                    const _Float16* __restrict__ W2T,
                                                    _Float16* __restrict__ X2) {
    __shared__ _Float16 Hs[64 * LDK];
    __shared__ _Float16 Ws[64 * LDK];
    const int tid  = threadIdx.x;
    const int wave = tid >> 6, lane = tid & 63;
    const int lm = lane & 15, lq = lane >> 4;
    const int row0 = blockIdx.x * 64;

    const int r = tid >> 2, cch = (tid & 3) * 32;
    int hrow = row0 + r; if (hrow >= N_NODES) hrow = N_NODES - 1;
    const _Float16* hp = Hm + (size_t)hrow * HID + cch;
    const _Float16* wp = W2T + (size_t)r * HID + cch;
    _Float16* hd = &Hs[r * LDK + cch];
    _Float16* wd = &Ws[r * LDK + cch];
#pragma unroll
    for (int i = 0; i < 4; ++i) {
        *(f16x8*)(hd + i * 8) = *(const f16x8*)(hp + i * 8);
        *(f16x8*)(wd + i * 8) = *(const f16x8*)(wp + i * 8);
    }
    __syncthreads();

    f32x4 acc[4];
#pragma unroll
    for (int nt = 0; nt < 4; ++nt) acc[nt] = (f32x4){0.f, 0.f, 0.f, 0.f};
#pragma unroll
    for (int k0 = 0; k0 < HID; k0 += 32) {
        f16x8 af = *(const f16x8*)&Hs[(wave * 16 + lm) * LDK + k0 + lq * 8];
#pragma unroll
        for (int nt = 0; nt < 4; ++nt) {
            f16x8 bf = *(const f16x8*)&Ws[(nt * 16 + lm) * LDK + k0 + lq * 8];
            acc[nt] = __builtin_amdgcn_mfma_f32_16x16x32_f16(af, bf, acc[nt], 0, 0, 0);
        }
    }
#pragma unroll
    for (int i = 0; i < 4; ++i) {
        int row = row0 + wave * 16 + lq * 4 + i;
        if (row < N_NODES) {
            _Float16* o = X2 + (size_t)row * OUT + lm;
#pragma unroll
            for (int nt = 0; nt < 4; ++nt)
                o[nt * 16] = (_Float16)acc[nt][i];
        }
    }
}

// ---------- agg2: out = gather-sum(X2)*in_norm + b2  (fp32 out) ----------
__global__ __launch_bounds__(256) void k_agg2(const _Float16* __restrict__ X2, const int* __restrict__ rp,
                                              const int* __restrict__ esrc, const float* __restrict__ innorm,
                                              const float* __restrict__ b2, float* __restrict__ out) {
    const int n = blockIdx.x * 8 + (threadIdx.x >> 5);
    const int c = (threadIdx.x & 31) << 1;
    if (n >= N_NODES) return;
    const int e0 = rp[n], e1 = rp[n + 1];
    float a0 = 0.f, a1 = 0.f;
    int e = e0;
    for (; e + 3 < e1; e += 4) {
        int s0 = esrc[e], s1 = esrc[e + 1], s2 = esrc[e + 2], s3 = esrc[e + 3];
        f16x2 v0 = *(const f16x2*)&X2[(size_t)s0 * OUT + c];
        f16x2 v1 = *(const f16x2*)&X2[(size_t)s1 * OUT + c];
        f16x2 v2 = *(const f16x2*)&X2[(size_t)s2 * OUT + c];
        f16x2 v3 = *(const f16x2*)&X2[(size_t)s3 * OUT + c];
        a0 += ((float)v0.x + (float)v1.x) + ((float)v2.x + (float)v3.x);
        a1 += ((float)v0.y + (float)v1.y) + ((float)v2.y + (float)v3.y);
    }
    for (; e < e1; ++e) {
        f16x2 v = *(const f16x2*)&X2[(size_t)esrc[e] * OUT + c];
        a0 += (float)v.x; a1 += (float)v.y;
    }
    float inn = innorm[n];
    float2 b = *(const float2*)&b2[c];
    *(float2*)&out[(size_t)n * OUT + c] = make_float2(a0 * inn + b.x, a1 * inn + b.y);
}

extern "C" void kernel_launch(void* const* d_in, const int* in_sizes, int n_in,
                              void* d_out, int out_size, void* d_ws, size_t ws_size,
                              hipStream_t stream) {
    const float* feat = (const float*)d_in[0];
    const float* W1   = (const float*)d_in[1];
    const float* b1   = (const float*)d_in[2];
    const float* W2   = (const float*)d_in[3];
    const float* b2   = (const float*)d_in[4];
    const void*  srcp = (const void*)d_in[5];
    const void*  dstp = (const void*)d_in[6];
    const int    E    = in_sizes[5];
    float* out = (float*)d_out;

    char* w = (char*)d_ws;
    size_t off = 0;
    auto alloc = [&](size_t bytes) -> void* {
        off = (off + 255) & ~(size_t)255;
        void* p = w + off;
        off += bytes;
        return p;
    };
    int*   hist    = (int*)alloc((size_t)NBUCK * NB * 4);
    int*   bsum    = (int*)alloc((size_t)NBUCK * 4);
    int*   bb      = (int*)alloc((size_t)(NBUCK + 1) * 4);
    int*   rp      = (int*)alloc((size_t)(N_NODES + 1) * 4);
    unsigned int* spart = (unsigned int*)alloc((size_t)SB * NBINS32 * 4);
    int*   tmp_src = (int*)alloc((size_t)E * 4);
    unsigned char* tmp_dl = (unsigned char*)alloc((size_t)E);
    int*   esrc    = (int*)alloc((size_t)E * 4);
    float* onorm   = (float*)alloc((size_t)N_NODES * 4);
    float* innorm  = (float*)alloc((size_t)N_NODES * 4);
    _Float16* W1T  = (_Float16*)alloc((size_t)IN_SIZE * HID * 2);
    _Float16* W2T  = (_Float16*)alloc((size_t)HID * OUT * 2);
    _Float16* X1   = (_Float16*)alloc((size_t)N_NODES * HID * 2);
    _Float16* Hbuf = (_Float16*)alloc((size_t)N_NODES * HID * 2);
    _Float16* X2   = (_Float16*)alloc((size_t)N_NODES * OUT * 2);
    (void)ws_size; (void)n_in; (void)out_size;

    const int EPB = (E + NB - 1) / NB;
    const int ESB = (E + SB - 1) / SB;
    const int WTB = (IN_SIZE * HID + HID * OUT + 255) / 256;

    // CSR build (dst side, LDS-atomic counting sort) — no global atomics anywhere
    k_chist_wt<<<NB + WTB, 256, 0, stream>>>(dstp, hist, E, EPB, W1, W1T, W2, W2T);
    k_srchist<<<SB, 256, 0, stream>>>(srcp, spart, E, ESB);
    k_sred<<<(NBINS32 + 255) / 256, 256, 0, stream>>>(spart, onorm);
    k_scanA<<<NBUCK, 256, 0, stream>>>(hist, bsum);
    k_scanB<<<1, 512, 0, stream>>>(bsum, bb);
    k_cscatter<<<NB, 256, 0, stream>>>(srcp, dstp, hist, bb, tmp_src, tmp_dl, E, EPB);
    k_fine<<<NBUCK, 256, 0, stream>>>(tmp_src, tmp_dl, bb, rp, esrc, innorm);

    // dense + aggregation pipeline
    k_gemm1_mfma<<<(N_NODES + 63) / 64, 256, 0, stream>>>(feat, W1T, onorm, X1);
    k_agg1<<<(N_NODES + 3) / 4, 256, 0, stream>>>(X1, rp, esrc, innorm, onorm, b1, Hbuf);
    k_gemm2_mfma<<<(N_NODES + 63) / 64, 256, 0, stream>>>(Hbuf, W2T, X2);
    k_agg2<<<(N_NODES + 7) / 8, 256, 0, stream>>>(X2, rp, esrc, innorm, b2, out);
}